// Round 6
// baseline (48.726 us; speedup 1.0000x reference)
//
#include <hip/hip_runtime.h>

#define B_    32
#define T_    1000
#define F_    80
#define COUT_ 64
#define NAUX_ 128
#define TO_   500
#define FO_   40
#define PSTR_ 12   // per-(b,c) param stride in floats: 9 filter + 1 bias + 2 pad
#define CL_   8    // channels per block-column (register window reuse)

#define NROWS          (B_ * COUT_ * TO_)   // 1,024,000 output rows
#define FSLICES        64                   // zero-fill y-slices
#define ROWS_PER_SLICE (NROWS / FSLICES)    // 16000

typedef float v4f __attribute__((ext_vector_type(4)));

// Kernel 1: hypernetwork, 4 threads per dot product (32-elem partials + shfl reduce).
__global__ __launch_bounds__(256) void hyper_kernel(
    const float* __restrict__ aux,
    const float* __restrict__ Wg,
    const float* __restrict__ bg,
    const float* __restrict__ Wb,
    const float* __restrict__ bb,
    const int*   __restrict__ x_len,
    float* __restrict__ fw,
    float* __restrict__ l2_out)
{
    const int NFT = B_ * 576 * 4;   // 73728 filter-dot threads
    const int NBT = B_ * 64 * 4;    // 8192 bias-dot threads
    int t = blockIdx.x * blockDim.x + threadIdx.x;

    if (t < NFT) {
        int d = t >> 2, part = t & 3;       // 4-lane groups aligned in wave
        int b = d / 576, idx = d % 576;
        const float* a = aux + b * NAUX_ + part * 32;
        const float* w = Wg + (size_t)idx * NAUX_ + part * 32;
        float s = 0.f;
        #pragma unroll
        for (int n = 0; n < 32; n += 4) {
            float4 av = *(const float4*)(a + n);
            float4 wv = *(const float4*)(w + n);
            s = fmaf(av.x, wv.x, s);
            s = fmaf(av.y, wv.y, s);
            s = fmaf(av.z, wv.z, s);
            s = fmaf(av.w, wv.w, s);
        }
        s += __shfl_xor(s, 1);
        s += __shfl_xor(s, 2);
        if (part == 0) {
            int c = idx / 9, k = idx % 9;
            fw[(b * COUT_ + c) * PSTR_ + k] = s + bg[idx];
        }
    } else if (t < NFT + NBT) {
        int u = t - NFT;
        int d = u >> 2, part = u & 3;
        int b = d >> 6, c = d & 63;
        const float* a = aux + b * NAUX_ + part * 32;
        const float* w = Wb + c * NAUX_ + part * 32;
        float s = 0.f;
        #pragma unroll
        for (int n = 0; n < 32; n += 4) {
            float4 av = *(const float4*)(a + n);
            float4 wv = *(const float4*)(w + n);
            s = fmaf(av.x, wv.x, s);
            s = fmaf(av.y, wv.y, s);
            s = fmaf(av.z, wv.z, s);
            s = fmaf(av.w, wv.w, s);
        }
        s += __shfl_xor(s, 1);
        s += __shfl_xor(s, 2);
        if (part == 0) fw[d * PSTR_ + 9] = s + bb[c];
    } else if (t < NFT + NBT + B_) {
        int b = t - NFT - NBT;
        l2_out[b] = (float)(x_len[b] >> 1);
    }
}

// Kernel 2: heterogeneous blocks in one dispatch.
//   blockIdx.y % 5 == 4  -> zero-fill slice: coalesced NT stores of all masked rows
//   else                 -> compute slice: conv+bias+relu+pool on ACTIVE rows only
// Fill and compute touch disjoint bytes (same l2 predicate). Interleaved dispatch
// order co-schedules store-only waves with FMA-heavy waves (m114 overlap).
__global__ __launch_bounds__(256) void conv_pool_kernel(
    const float* __restrict__ x,      // [B][T][F]
    const int*   __restrict__ x_len,
    const float* __restrict__ fw,     // [B*COUT][PSTR_]
    float* __restrict__ out)          // [B][COUT][TO][FO]
{
    const int by    = blockIdx.y;     // [0, 320)
    const int phase = by % 5;
    int t = blockIdx.x * blockDim.x + threadIdx.x;   // [0, 5120)

    if (phase == 4) {
        // ---- zero-fill slice ----
        const int fs = by / 5;                // [0, 64)
        const int f4 = t % 10;
        const int rb = t / 10;                // [0, 512)
        const int rend = (fs + 1) * ROWS_PER_SLICE;
        for (int r = fs * ROWS_PER_SLICE + rb; r < rend; r += 512) {
            int bc = r / TO_;                 // const-divisor -> magic mul
            int to = r - bc * TO_;
            int b  = bc >> 6;
            int l2 = x_len[b] >> 1;
            if (to >= l2) {
                v4f z = (v4f){0.f, 0.f, 0.f, 0.f};
                __builtin_nontemporal_store(z, (v4f*)(out + (size_t)r * FO_ + 4 * f4));
            }
        }
        return;
    }

    // ---- compute slice ----
    const int cs  = (by / 5) * 4 + phase;     // [0, 256)
    const int b   = cs >> 3;
    const int bc0 = cs * CL_;                 // b*64 + g*8

    if (t >= TO_ * 10) return;                // 5000 active of 5120
    int f4 = t % 10;
    int to = t / 10;

    int l2 = x_len[b] >> 1;
    if (to >= l2) return;                     // masked: fill slices own these bytes

    float* obase = out + ((size_t)bc0 * TO_ + to) * FO_ + 4 * f4;

    // 4x10 input window: rows 2to-1..2to+2, input cols 8f4-1..8f4+8 (zero-padded)
    float w[4][10];
    const float* xb = x + (size_t)b * (T_ * F_);
    const int cbase = 8 * f4;
    #pragma unroll
    for (int i = 0; i < 4; ++i) {
        int r = 2 * to - 1 + i;
        if (r < 0 || r >= T_) {
            #pragma unroll
            for (int j = 0; j < 10; ++j) w[i][j] = 0.f;
        } else {
            const float* rp = xb + r * F_ + cbase;   // 16B-aligned
            w[i][0] = (f4 > 0) ? rp[-1] : 0.f;
            float4 m0 = *(const float4*)(rp);
            float4 m1 = *(const float4*)(rp + 4);
            w[i][1] = m0.x; w[i][2] = m0.y; w[i][3] = m0.z; w[i][4] = m0.w;
            w[i][5] = m1.x; w[i][6] = m1.y; w[i][7] = m1.z; w[i][8] = m1.w;
            w[i][9] = (f4 < 9) ? rp[8] : 0.f;
        }
    }

    const float* p = fw + (size_t)bc0 * PSTR_;       // wave-uniform
    #pragma unroll 1
    for (int i = 0; i < CL_; ++i) {
        float4 p0 = *(const float4*)(p);
        float4 p1 = *(const float4*)(p + 4);
        float4 p2 = *(const float4*)(p + 8);
        const float Flt[9] = {p0.x, p0.y, p0.z, p0.w, p1.x, p1.y, p1.z, p1.w, p2.x};
        const float bias = p2.y;
        p += PSTR_;

        float o[4];
        #pragma unroll
        for (int q = 0; q < 4; ++q) {
            float s00 = 0.f, s01 = 0.f, s10 = 0.f, s11 = 0.f;
            #pragma unroll
            for (int ii = 0; ii < 3; ++ii) {
                #pragma unroll
                for (int jj = 0; jj < 3; ++jj) {
                    const float flt = Flt[ii * 3 + jj];
                    s00 = fmaf(flt, w[ii][2 * q + jj],     s00);
                    s01 = fmaf(flt, w[ii][2 * q + 1 + jj], s01);
                    s10 = fmaf(flt, w[ii + 1][2 * q + jj],     s10);
                    s11 = fmaf(flt, w[ii + 1][2 * q + 1 + jj], s11);
                }
            }
            float m = fmaxf(fmaxf(s00, s01), fmaxf(s10, s11));
            o[q] = fmaxf(m + bias, 0.f);
        }
        v4f ov = (v4f){o[0], o[1], o[2], o[3]};
        __builtin_nontemporal_store(ov, (v4f*)(obase + (size_t)i * (TO_ * FO_)));
    }
}

extern "C" void kernel_launch(void* const* d_in, const int* in_sizes, int n_in,
                              void* d_out, int out_size, void* d_ws, size_t ws_size,
                              hipStream_t stream) {
    const float* x     = (const float*)d_in[0];
    const int*   x_len = (const int*)d_in[1];
    const float* aux   = (const float*)d_in[2];
    const float* Wg    = (const float*)d_in[3];
    const float* bg    = (const float*)d_in[4];
    const float* Wb    = (const float*)d_in[5];
    const float* bb    = (const float*)d_in[6];

    float* out = (float*)d_out;
    float* fw  = (float*)d_ws;                             // B*COUT*PSTR_ floats = 98 KB
    float* l2_out = out + (size_t)B_ * COUT_ * TO_ * FO_;  // tail: 32 floats

    // Kernel 1: 73728 + 8192 + 32 = 81952 threads -> 321 blocks
    {
        int total = B_ * 576 * 4 + B_ * 64 * 4 + B_;
        int blocks = (total + 255) / 256;
        hipLaunchKernelGGL(hyper_kernel, dim3(blocks), dim3(256), 0, stream,
                           aux, Wg, bg, Wb, bb, x_len, fw, l2_out);
    }
    // Kernel 2: grid (20, 320): 256 compute slices + 64 fill slices, interleaved 4:1
    {
        hipLaunchKernelGGL(conv_pool_kernel, dim3(20, 320), dim3(256), 0, stream,
                           x, x_len, fw, out);
    }
}

// Round 8
// 45.054 us; speedup vs baseline: 1.0815x; 1.0815x over previous
//
#include <hip/hip_runtime.h>
#include <hip/hip_fp16.h>
#include <stdint.h>

#define B_    32
#define T_    1000
#define F_    80
#define COUT_ 64
#define NAUX_ 128
#define TO_   500
#define FO_   40
#define PSTR_ 12   // per-(b,c) param stride in u32: 9 dup-half2 taps + 1 f32 bias + 2 pad
#define CL_   8    // channels per block-column (register window reuse)

typedef float v4f __attribute__((ext_vector_type(4)));

// Kernel 1: hypernetwork, 4 threads per dot product (32-elem partials + shfl reduce).
// Filter taps stored as DUPLICATED half2 (h,h) in u32; bias stored as f32 bits.
__global__ __launch_bounds__(256) void hyper_kernel(
    const float* __restrict__ aux,
    const float* __restrict__ Wg,
    const float* __restrict__ bg,
    const float* __restrict__ Wb,
    const float* __restrict__ bb,
    const int*   __restrict__ x_len,
    uint32_t* __restrict__ fw,
    float* __restrict__ l2_out)
{
    const int NFT = B_ * 576 * 4;   // 73728 filter-dot threads
    const int NBT = B_ * 64 * 4;    // 8192 bias-dot threads
    int t = blockIdx.x * blockDim.x + threadIdx.x;

    if (t < NFT) {
        int d = t >> 2, part = t & 3;       // 4-lane groups aligned in wave
        int b = d / 576, idx = d % 576;
        const float* a = aux + b * NAUX_ + part * 32;
        const float* w = Wg + (size_t)idx * NAUX_ + part * 32;
        float s = 0.f;
        #pragma unroll
        for (int n = 0; n < 32; n += 4) {
            float4 av = *(const float4*)(a + n);
            float4 wv = *(const float4*)(w + n);
            s = fmaf(av.x, wv.x, s);
            s = fmaf(av.y, wv.y, s);
            s = fmaf(av.z, wv.z, s);
            s = fmaf(av.w, wv.w, s);
        }
        s += __shfl_xor(s, 1);
        s += __shfl_xor(s, 2);
        if (part == 0) {
            int c = idx / 9, k = idx % 9;
            uint32_t hu = (uint32_t)__half_as_ushort(__float2half_rn(s + bg[idx]));
            fw[(b * COUT_ + c) * PSTR_ + k] = hu | (hu << 16);
        }
    } else if (t < NFT + NBT) {
        int u = t - NFT;
        int d = u >> 2, part = u & 3;
        int b = d >> 6, c = d & 63;
        const float* a = aux + b * NAUX_ + part * 32;
        const float* w = Wb + c * NAUX_ + part * 32;
        float s = 0.f;
        #pragma unroll
        for (int n = 0; n < 32; n += 4) {
            float4 av = *(const float4*)(a + n);
            float4 wv = *(const float4*)(w + n);
            s = fmaf(av.x, wv.x, s);
            s = fmaf(av.y, wv.y, s);
            s = fmaf(av.z, wv.z, s);
            s = fmaf(av.w, wv.w, s);
        }
        s += __shfl_xor(s, 1);
        s += __shfl_xor(s, 2);
        if (part == 0) fw[d * PSTR_ + 9] = __float_as_uint(s + bb[c]);
    } else if (t < NFT + NBT + B_) {
        int b = t - NFT - NBT;
        l2_out[b] = (float)(x_len[b] >> 1);
    }
}

// Kernel 2: fused conv(3x3,pad1) + bias + relu + maxpool(2x2,s2) + time mask.
// Packed-f16 math: each __hfma2 computes the two pool rows (s0x in lo, s1x in hi).
// Window built once per thread as 3x10 vertical half2 pairs, reused over 8 channels.
__global__ __launch_bounds__(256) void conv_pool_kernel(
    const float*    __restrict__ x,      // [B][T][F]
    const int*      __restrict__ x_len,
    const uint32_t* __restrict__ fw,     // [B*COUT][PSTR_] dup-half2 taps + f32 bias
    float* __restrict__ out)             // [B][COUT][TO][FO]
{
    const int bg  = blockIdx.y;       // b*8 + g
    const int b   = bg >> 3;
    const int bc0 = bg * CL_;         // b*64 + g*8

    int t = blockIdx.x * blockDim.x + threadIdx.x;   // [0, 5120)
    if (t >= TO_ * 10) return;                       // 5000 active
    int f4 = t % 10;
    int to = t / 10;

    float* obase = out + ((size_t)bc0 * TO_ + to) * FO_ + 4 * f4;

    int l2 = x_len[b] >> 1;
    if (to >= l2) {
        v4f z = (v4f){0.f, 0.f, 0.f, 0.f};
        #pragma unroll
        for (int i = 0; i < CL_; ++i)
            __builtin_nontemporal_store(z, (v4f*)(obase + (size_t)i * (TO_ * FO_)));
        return;
    }

    // 4x10 input window: rows 2to-1..2to+2, input cols 8f4-1..8f4+8 (zero-padded)
    float w[4][10];
    const float* xb = x + (size_t)b * (T_ * F_);
    const int cbase = 8 * f4;
    #pragma unroll
    for (int i = 0; i < 4; ++i) {
        int r = 2 * to - 1 + i;
        if (r < 0 || r >= T_) {
            #pragma unroll
            for (int j = 0; j < 10; ++j) w[i][j] = 0.f;
        } else {
            const float* rp = xb + r * F_ + cbase;   // 16B-aligned
            w[i][0] = (f4 > 0) ? rp[-1] : 0.f;
            float4 m0 = *(const float4*)(rp);
            float4 m1 = *(const float4*)(rp + 4);
            w[i][1] = m0.x; w[i][2] = m0.y; w[i][3] = m0.z; w[i][4] = m0.w;
            w[i][5] = m1.x; w[i][6] = m1.y; w[i][7] = m1.z; w[i][8] = m1.w;
            w[i][9] = (f4 < 9) ? rp[8] : 0.f;
        }
    }

    // vertical half2 pairs: wp[ii][c] = (w[ii][c], w[ii+1][c])
    __half2 wp[3][10];
    #pragma unroll
    for (int ii = 0; ii < 3; ++ii)
        #pragma unroll
        for (int c = 0; c < 10; ++c)
            wp[ii][c] = __halves2half2(__float2half_rn(w[ii][c]),
                                       __float2half_rn(w[ii + 1][c]));

    const uint32_t* p = fw + (size_t)bc0 * PSTR_;    // wave-uniform -> s_load
    #pragma unroll 1
    for (int i = 0; i < CL_; ++i) {
        __half2 flt[9];
        #pragma unroll
        for (int k = 0; k < 9; ++k)
            flt[k] = *(const __half2*)(p + k);       // duplicated (h,h)
        const float bias = __uint_as_float(p[9]);
        p += PSTR_;

        float o[4];
        #pragma unroll
        for (int q = 0; q < 4; ++q) {
            __half2 acc0 = __halves2half2(__ushort_as_half((unsigned short)0),
                                          __ushort_as_half((unsigned short)0));
            __half2 acc1 = acc0;
            #pragma unroll
            for (int ii = 0; ii < 3; ++ii) {
                #pragma unroll
                for (int jj = 0; jj < 3; ++jj) {
                    const __half2 f = flt[ii * 3 + jj];
                    acc0 = __hfma2(f, wp[ii][2 * q + jj],     acc0);  // (s00,s10)
                    acc1 = __hfma2(f, wp[ii][2 * q + 1 + jj], acc1);  // (s01,s11)
                }
            }
            float a0 = __half2float(__low2half(acc0));
            float a1 = __half2float(__high2half(acc0));
            float b0 = __half2float(__low2half(acc1));
            float b1 = __half2float(__high2half(acc1));
            float m  = fmaxf(fmaxf(a0, a1), fmaxf(b0, b1));
            o[q] = fmaxf(m + bias, 0.f);
        }
        v4f ov = (v4f){o[0], o[1], o[2], o[3]};
        __builtin_nontemporal_store(ov, (v4f*)(obase + (size_t)i * (TO_ * FO_)));
    }
}

extern "C" void kernel_launch(void* const* d_in, const int* in_sizes, int n_in,
                              void* d_out, int out_size, void* d_ws, size_t ws_size,
                              hipStream_t stream) {
    const float* x     = (const float*)d_in[0];
    const int*   x_len = (const int*)d_in[1];
    const float* aux   = (const float*)d_in[2];
    const float* Wg    = (const float*)d_in[3];
    const float* bg    = (const float*)d_in[4];
    const float* Wb    = (const float*)d_in[5];
    const float* bb    = (const float*)d_in[6];

    float*    out = (float*)d_out;
    uint32_t* fw  = (uint32_t*)d_ws;                       // B*COUT*PSTR_ u32 = 98 KB
    float* l2_out = out + (size_t)B_ * COUT_ * TO_ * FO_;  // tail: 32 floats

    // Kernel 1: 73728 + 8192 + 32 = 81952 threads -> 321 blocks
    {
        int total = B_ * 576 * 4 + B_ * 64 * 4 + B_;
        int blocks = (total + 255) / 256;
        hipLaunchKernelGGL(hyper_kernel, dim3(blocks), dim3(256), 0, stream,
                           aux, Wg, bg, Wb, bb, x_len, fw, l2_out);
    }
    // Kernel 2: grid (20, 256) = 5120 threads per (b,g), 256 (b,g) pairs
    {
        hipLaunchKernelGGL(conv_pool_kernel, dim3(20, 256), dim3(256), 0, stream,
                           x, x_len, fw, out);
    }
}